// Round 9
// baseline (431.965 us; speedup 1.0000x reference)
//
#include <hip/hip_runtime.h>
#include <hip/hip_bf16.h>

typedef __bf16 bf16x8 __attribute__((ext_vector_type(8)));
typedef float f32x4 __attribute__((ext_vector_type(4)));
using u16 = unsigned short;
using u32 = unsigned int;

__device__ __forceinline__ float bf2f(u16 v) {
    unsigned int u = (unsigned int)v << 16;
    float f; __builtin_memcpy(&f, &u, 4); return f;
}
__device__ __forceinline__ u16 f2bf(float f) {
    unsigned int u; __builtin_memcpy(&u, &f, 4);
    u += 0x7FFFu + ((u >> 16) & 1u);   // RNE (finite data only)
    return (u16)(u >> 16);
}

// ---------------------------------------------------------------------------
// Bulk fp32 -> bf16 conversion, 9 segments, 8 elems/thread.
// ---------------------------------------------------------------------------
struct Cvt9 {
    const float* src[9];
    u16* dst[9];
    int end[9];      // cumulative chunk ends (chunks of 8 elems)
};
__global__ __launch_bounds__(256) void cvt_all(Cvt9 d, int total)
{
    int c = blockIdx.x * 256 + threadIdx.x;
    if (c >= total) return;
    int seg = 0;
    while (c >= d.end[seg]) ++seg;
    int local = c - (seg ? d.end[seg - 1] : 0);
    const float* s = d.src[seg] + (size_t)local * 8;
    float4 f0 = *(const float4*)s;
    float4 f1 = *(const float4*)(s + 4);
    u16 tmp[8] = { f2bf(f0.x), f2bf(f0.y), f2bf(f0.z), f2bf(f0.w),
                   f2bf(f1.x), f2bf(f1.y), f2bf(f1.z), f2bf(f1.w) };
    *(uint4*)(d.dst[seg] + (size_t)local * 8) = *(const uint4*)tmp;
}

// ---------------------------------------------------------------------------
// Bias concatenation (fp32 copy, 7 segments).
// ---------------------------------------------------------------------------
struct Cpy7 {
    const float* src[7];
    float* dst[7];
    int end[7];
};
__global__ __launch_bounds__(256) void copy_f32(Cpy7 d, int total)
{
    int c = blockIdx.x * 256 + threadIdx.x;
    if (c >= total) return;
    int seg = 0;
    while (c >= d.end[seg]) ++seg;
    int local = c - (seg ? d.end[seg - 1] : 0);
    d.dst[seg][local] = d.src[seg][local];
}

// ---------------------------------------------------------------------------
// Pure-bf16 C = A @ B^T + bias GEMM, two independent "halves" selected by
// blockIdx.y < ysplit.  3-buffer LDS pipeline (BK=32, 48 KB), counted vmcnt,
// raw s_barrier; swapped-operand MFMA -> lane holds 4 consecutive C columns
// of one row (vectorized epilogue).
// v7: optional FUSED ROPE in the epilogue (per-half flag rp0/rp1): for
// colb >= 1024, apply the source-quirk rotation to the two col-pairs using
// pos = row & 511, i = ((col-1024)&63)/2 (matches the old rope_inplace,
// but applied pre-bf16-rounding).
// ---------------------------------------------------------------------------
template<bool CF>
__global__ __launch_bounds__(256) void gemm_v7(
    const u16* __restrict__ A0, const u16* __restrict__ B0, void* __restrict__ C0, const float* __restrict__ e0,
    const u16* __restrict__ A1, const u16* __restrict__ B1, void* __restrict__ C1, const float* __restrict__ e1,
    int ysplit, int lda, int ldb, int ldc, int N, int K, int rp0, int rp1)
{
    __shared__ __align__(16) u16 As[3][128 * 32];
    __shared__ __align__(16) u16 Bs[3][128 * 32];

    const int t = threadIdx.x;
    const int lane = t & 63;
    const int w = t >> 6;
    const int wm = w >> 1, wn = w & 1;
    const int l16 = lane & 15, quad = lane >> 4;
    const int m0 = blockIdx.x * 128;

    const u16* A; const u16* B; void* Cv; const float* bias; int yl; int rp;
    if ((int)blockIdx.y < ysplit) { A = A0; B = B0; Cv = C0; bias = e0; yl = blockIdx.y; rp = rp0; }
    else                          { A = A1; B = B1; Cv = C1; bias = e1; yl = blockIdx.y - ysplit; rp = rp1; }
    const int n0 = yl * 128;

    const int sub  = lane >> 2;                 // 0..15: row within 16-row chunk
    const int slot = lane & 3;                  // 16B slot within 64B row
    const int agc  = slot ^ ((sub >> 1) & 3);   // swizzled global chunk
    const int sfr  = (l16 >> 1) & 3;            // fragment-read unswizzle

    f32x4 acc[4][4];
#pragma unroll
    for (int i = 0; i < 4; ++i)
#pragma unroll
        for (int j = 0; j < 4; ++j) acc[i][j] = (f32x4){0.f, 0.f, 0.f, 0.f};

    auto STAGE = [&](int buf, int k0) {
#pragma unroll
        for (int c = 0; c < 2; ++c) {
            const int rr = w * 32 + c * 16;
            const u16* ga = A + (size_t)(m0 + rr + sub) * lda + k0 + agc * 8;
            __builtin_amdgcn_global_load_lds(
                (const __attribute__((address_space(1))) u32*)ga,
                (__attribute__((address_space(3))) u32*)&As[buf][rr * 32], 16, 0, 0);
            const u16* gb = B + (size_t)(n0 + rr + sub) * ldb + k0 + agc * 8;
            __builtin_amdgcn_global_load_lds(
                (const __attribute__((address_space(1))) u32*)gb,
                (__attribute__((address_space(3))) u32*)&Bs[buf][rr * 32], 16, 0, 0);
        }
    };

    const int nt = K >> 5;
    STAGE(0, 0);
    STAGE(1, 32);
    int cur = 0;
    for (int tt = 0; tt < nt; ++tt) {
        int pre = cur + 2; if (pre >= 3) pre -= 3;
        if (tt + 2 < nt) {
            STAGE(pre, (tt + 2) << 5);
            asm volatile("s_waitcnt vmcnt(8)");   // tile tt's 4 loads landed
        } else if (tt + 1 < nt) {
            asm volatile("s_waitcnt vmcnt(4)");
        } else {
            asm volatile("s_waitcnt vmcnt(0)");
        }
        __builtin_amdgcn_s_barrier();             // everyone's tile-tt loads landed

        const u16* Ab = As[cur];
        bf16x8 af[4], bfr[4];
#pragma unroll
        for (int i = 0; i < 4; ++i)
            af[i] = *(const bf16x8*)&Ab[(wm * 64 + i * 16 + l16) * 32 + (quad ^ sfr) * 8];
#pragma unroll
        for (int j = 0; j < 4; ++j)
            bfr[j] = *(const bf16x8*)&Bs[cur][(wn * 64 + j * 16 + l16) * 32 + (quad ^ sfr) * 8];
#pragma unroll
        for (int i = 0; i < 4; ++i)
#pragma unroll
            for (int j = 0; j < 4; ++j)
                acc[i][j] = __builtin_amdgcn_mfma_f32_16x16x32_bf16(bfr[j], af[i], acc[i][j], 0, 0, 0);

        __builtin_amdgcn_s_barrier();             // done reading cur -> restageable
        cur += 1; if (cur >= 3) cur -= 3;
    }

    // Swapped-operand C layout: acc[i][j][r] = C[m0+wm*64+i*16+l16]
    //                                           [n0+wn*64+j*16+quad*4+r]
#pragma unroll
    for (int i = 0; i < 4; ++i) {
        const int row = m0 + wm * 64 + i * 16 + l16;
#pragma unroll
        for (int j = 0; j < 4; ++j) {
            const int colb = n0 + wn * 64 + j * 16 + quad * 4;
            if (colb >= N) continue;
            float4 bv = *(const float4*)&bias[colb];
            float v0 = acc[i][j][0] + bv.x;
            float v1 = acc[i][j][1] + bv.y;
            float v2 = acc[i][j][2] + bv.z;
            float v3 = acc[i][j][3] + bv.w;
            if (rp && colb >= 1024) {             // fused rope (source quirk)
                const float LN = 0.2878231366242558f;   // ln(10000)/32
                int i0 = ((colb - 1024) & 63) >> 1;
                float th0 = __expf(-(float)i0 * LN);
                float th1 = __expf(-(float)(i0 + 1) * LN);
                float ps = (float)(row & 511);
                float a0 = ps * th0, a1 = ps * th1;
                float s0 = sinf(a0), c0 = cosf(a0);
                float s1 = sinf(a1), c1 = cosf(a1);
                float t0 = v0 * s0 - v1 * c0;
                float t1 = v1 * s0 + v0 * c0;
                float t2 = v2 * s1 - v3 * c1;
                float t3 = v3 * s1 + v2 * c1;
                v0 = t0; v1 = t1; v2 = t2; v3 = t3;
            }
            if (CF) {
                float4 out = { v0, v1, v2, v3 };
                *(float4*)((float*)Cv + (size_t)row * ldc + colb) = out;
            } else {
                u16 p[4] = { f2bf(v0), f2bf(v1), f2bf(v2), f2bf(v3) };
                *(uint2*)((u16*)Cv + (size_t)row * ldc + colb) = *(const uint2*)p;
            }
        }
    }
}

// ---------------------------------------------------------------------------
// Flash attention v9: QBLK=128, 8 waves (512 thr).  Wave w owns q rows
// w*16..w*16+15 of the 128-row tile; Ks/Vt staging amortized over 2x q rows
// (per-thread prefetch: 2 K + 1 V uint4).  LDS 45,056 B -> 3 WG/CU
// (24 waves/CU).  Swapped QK^T (lane owns q=l16), scalar online softmax in
// log2 domain with T13 defer-max (skip rescale when __all(mxC<=m2+11.54)).
// Ps: 128x72, granule-rotation swizzle (store b64 conflict-free, read b128
// at 8-lane/bank-group minimum).  Vt key-rotation swizzle.  Raw-barrier
// async staging (vmcnt NOT drained at barriers).  Grid 1024, temporal XCD
// swizzle: xcd=id&7, qt=(id>>3)&3, panel=xcd+8*(id>>5) -> 4 qt-sharers of a
// (b,h) K/V panel run back-to-back on one XCD.
// ---------------------------------------------------------------------------
__global__ __launch_bounds__(512) void attn_kernel(
    const u16* __restrict__ q_src,   // 8192 x 2048 : [q_c | q_r(roped)]
    const u16* __restrict__ kv_src,  // 8192 x 2048 : [k_c | v_c]
    const u16* __restrict__ kr_src,  // 8192 x 1088 : k_r at col 1024 (roped)
    u16* __restrict__ o_dst, int ldo)
{
    __shared__ __align__(16) u16 Ks[64 * 136];
    __shared__ __align__(16) u16 Vt[64 * 72];    // [vd][key] rotated
    __shared__ __align__(16) u16 Ps[128 * 72];   // [q][key] granule-rotated

    const int t = threadIdx.x;
    const int lane = t & 63;
    const int w = t >> 6;                        // 0..7
    const int l16 = lane & 15, quad = lane >> 4;
    const int a7 = l16 & 7;

    const int id   = blockIdx.x;                 // 0..1023
    const int xcd  = id & 7;
    const int qt   = (id >> 3) & 3;
    const int panel = xcd + ((id >> 5) << 3);    // 0..255
    const int h = panel & 15;
    const int b = panel >> 4;
    const int qrow0 = b * 512 + qt * 128;
    const int krow_base = b * 512;

    // Q fragments straight to registers: wave w owns q rows w*16..w*16+15.
    bf16x8 aq[4];
    {
        const u16* qrow = q_src + (size_t)(qrow0 + w * 16 + l16) * 2048;
#pragma unroll
        for (int ks = 0; ks < 4; ++ks) {
            int col = ks * 32 + quad * 8;
            const u16* src = (col < 64) ? qrow + h * 64 + col
                                        : qrow + 1024 + h * 64 + (col - 64);
            aq[ks] = *(const bf16x8*)src;
        }
    }

    // --- staging geometry (kt-independent, 512 threads) ---
    const int colK = (t & 15) * 8;            // K column chunk (u16)
    const int r0k  = t >> 4;                  // K row 0..31 (+32)
    const u16* kbase; int kstr;
    if (colK < 64) { kbase = kv_src + h * 64 + colK;        kstr = 2048; }
    else           { kbase = kr_src + 1024 + (colK - 64);   kstr = 1088; }
    u16* kw = &Ks[r0k * 136 + colK];

    const int v00 = (t & 7) * 8;              // vd chunk
    const int r0v = t >> 3;                   // key row 0..63
    const u16* vbase = kv_src + 1024 + h * 64 + v00;
    const int rotA = (r0v + v00) & 63;
    u16* vwA = &Vt[v00 * 72 + rotA];

    auto LOADT = [&](int krow0, uint4& K0, uint4& K1, uint4& V0) {
        K0 = *(const uint4*)(kbase + (size_t)(krow0 + r0k     ) * kstr);
        K1 = *(const uint4*)(kbase + (size_t)(krow0 + r0k + 32) * kstr);
        V0 = *(const uint4*)(vbase + (size_t)(krow0 + r0v     ) * 2048);
    };
    auto WRITET = [&](const uint4& K0, const uint4& K1, const uint4& V0) {
        *(uint4*)(kw)            = K0;
        *(uint4*)(kw + 32 * 136) = K1;
        u16 ta[8];
        __builtin_memcpy(ta, &V0, 16);
#pragma unroll
        for (int j2 = 0; j2 < 8; ++j2) vwA[j2 * 72] = ta[j2];
    };

    float m2 = -1e30f, l_run = 0.f;           // per-lane: q-row l16 (log2 dom.)
    f32x4 o[4];
#pragma unroll
    for (int n = 0; n < 4; ++n) o[n] = (f32x4){0.f, 0.f, 0.f, 0.f};

    const float C = 0.10411756f;              // log2(e)/sqrt(192)
    const float THR2 = 11.5419f;              // defer-max: 8 * log2(e)

    uint4 kA0, kA1, vA0;
    uint4 kB0, kB1, vB0;
    LOADT(krow_base, kA0, kA1, vA0);          // kt = 0

    for (int kt = 0; kt < 8; ++kt) {
        // (A) all waves done reading Ks/Vt of previous tile
        __builtin_amdgcn_s_barrier();
        if ((kt & 1) == 0) {
            WRITET(kA0, kA1, vA0);
            if (kt < 7) LOADT(krow_base + (kt + 1) * 64, kB0, kB1, vB0);
        } else {
            WRITET(kB0, kB1, vB0);
            if (kt < 7) LOADT(krow_base + (kt + 1) * 64, kA0, kA1, vA0);
        }
        asm volatile("s_waitcnt lgkmcnt(0)");     // my ds_writes visible
        __builtin_amdgcn_sched_barrier(0);
        // (B) everyone's ds_writes visible; vmcnt NOT drained -> prefetch flies
        __builtin_amdgcn_s_barrier();

        // S strip, SWAPPED: s[n] = K_n Q^T -> lane holds S[key=16n+4q+r][q=l16]
        f32x4 s[4];
#pragma unroll
        for (int n = 0; n < 4; ++n) s[n] = (f32x4){0.f, 0.f, 0.f, 0.f};
#pragma unroll
        for (int ks = 0; ks < 4; ++ks) {
#pragma unroll
            for (int n = 0; n < 4; ++n) {
                bf16x8 bk = *(const bf16x8*)&Ks[(n * 16 + l16) * 136 + ks * 32 + quad * 8];
                s[n] = __builtin_amdgcn_mfma_f32_16x16x32_bf16(bk, aq[ks], s[n], 0, 0, 0);
            }
        }

        // online softmax (log2 domain), row = q = l16 per lane
        float mx = fmaxf(fmaxf(s[0][0], s[0][1]), fmaxf(s[0][2], s[0][3]));
#pragma unroll
        for (int n = 1; n < 4; ++n)
            mx = fmaxf(mx, fmaxf(fmaxf(s[n][0], s[n][1]), fmaxf(s[n][2], s[n][3])));
        mx = fmaxf(mx, __shfl_xor(mx, 16));
        mx = fmaxf(mx, __shfl_xor(mx, 32));
        float mxC = mx * C;

        if (__all(mxC <= m2 + THR2)) {
            // T13 defer-max: keep m2, alpha == 1, no o-rescale.
            float rs = 0.f;
#pragma unroll
            for (int n = 0; n < 4; ++n)
#pragma unroll
                for (int r = 0; r < 4; ++r) {
                    float pv = __builtin_amdgcn_exp2f(__builtin_fmaf(s[n][r], C, -m2));
                    s[n][r] = pv;
                    rs += pv;
                }
            rs += __shfl_xor(rs, 16);
            rs += __shfl_xor(rs, 32);
            l_run += rs;
        } else {
            float mnew = fmaxf(m2, mxC);
            float alpha = __builtin_amdgcn_exp2f(m2 - mnew);
            m2 = mnew;
            float rs = 0.f;
#pragma unroll
            for (int n = 0; n < 4; ++n)
#pragma unroll
                for (int r = 0; r < 4; ++r) {
                    float pv = __builtin_amdgcn_exp2f(__builtin_fmaf(s[n][r], C, -mnew));
                    s[n][r] = pv;
                    rs += pv;
                }
            rs += __shfl_xor(rs, 16);
            rs += __shfl_xor(rs, 32);
            l_run = l_run * alpha + rs;

            // redistribute alpha to o-layout rows (q = quad*4+r at lane q<16)
            float aO[4];
#pragma unroll
            for (int r = 0; r < 4; ++r) aO[r] = __shfl(alpha, quad * 4 + r);
#pragma unroll
            for (int n = 0; n < 4; ++n)
#pragma unroll
                for (int r = 0; r < 4; ++r) o[n][r] *= aO[r];
        }

        // P -> LDS: row q=w*16+l16 (wave-private); granule rotation
        // p=(g+a7)&7, one b64 store per n (conflict-free).
        {
            u16* prow = &Ps[(w * 16 + l16) * 72];
#pragma unroll
            for (int n = 0; n < 4; ++n) {
                int p = (2 * n + (quad >> 1) + a7) & 7;
                u32 p0 = (u32)f2bf(s[n][0]) | ((u32)f2bf(s[n][1]) << 16);
                u32 p1 = (u32)f2bf(s[n][2]) | ((u32)f2bf(s[n][3]) << 16);
                uint2 pp = { p0, p1 };
                *(uint2*)&prow[p * 8 + (quad & 1) * 4] = pp;
            }
        }

        // O += P @ V; Ps read undoes the granule rotation (g = 4kk+quad)
#pragma unroll
        for (int kk = 0; kk < 2; ++kk) {
            bf16x8 ap = *(const bf16x8*)&Ps[(w * 16 + l16) * 72
                          + (((4 * kk + quad + a7) & 7) << 3)];
#pragma unroll
            for (int n = 0; n < 4; ++n) {
                bf16x8 bv = *(const bf16x8*)&Vt[(n * 16 + l16) * 72
                              + ((kk * 32 + quad * 8 + n * 16 + (l16 & 8)) & 63)];
                o[n] = __builtin_amdgcn_mfma_f32_16x16x32_bf16(ap, bv, o[n], 0, 0, 0);
            }
        }
    }

    // epilogue: inv(l_run) lives at lane q (<16); o rows are quad*4+r
    float inv = 1.0f / l_run;
#pragma unroll
    for (int r = 0; r < 4; ++r) {
        float invO = __shfl(inv, quad * 4 + r);
        int row = qrow0 + w * 16 + quad * 4 + r;
#pragma unroll
        for (int n = 0; n < 4; ++n) {
            int col = h * 64 + n * 16 + l16;
            o_dst[(size_t)row * ldo + col] = f2bf(o[n][r] * invO);
        }
    }
}

// ---------------------------------------------------------------------------
extern "C" void kernel_launch(void* const* d_in, const int* in_sizes, int n_in,
                              void* d_out, int out_size, void* d_ws, size_t ws_size,
                              hipStream_t stream)
{
    const float* h    = (const float*)d_in[0];
    const float* Wdkv = (const float*)d_in[1];
    const float* bdkv = (const float*)d_in[2];
    const float* Wuk  = (const float*)d_in[3];
    const float* buk  = (const float*)d_in[4];
    const float* Wuv  = (const float*)d_in[5];
    const float* buv  = (const float*)d_in[6];
    const float* Wdq  = (const float*)d_in[7];
    const float* bdq  = (const float*)d_in[8];
    const float* Wuq  = (const float*)d_in[9];
    const float* buq  = (const float*)d_in[10];
    const float* Wqr  = (const float*)d_in[11];
    const float* bqr  = (const float*)d_in[12];
    const float* Wkr  = (const float*)d_in[13];
    const float* bkr  = (const float*)d_in[14];
    const float* Wfc  = (const float*)d_in[15];
    const float* bfc  = (const float*)d_in[16];

    // Workspace layout (98,062,592 B total):
    //   out1      : 8192 x 1088 bf16  [c_kv | c_q | k_r]; attn out -> cols 0..1023
    //   out2a/hbf : 8192 x 2048 bf16  (h-bf16 during stage 1; [k_c|v_c] after)
    //   out2b     : 8192 x 2048 bf16  [q_c | q_r]
    //   w1        : 1152 x 2048 bf16  [Wdkv;Wdq;Wkr;zero-pad]
    //   w2a,w2b   : 2048 x 512 bf16   [Wuk;Wuv], [Wuq;Wqr]
    //   wfc       : 2048 x 1024 bf16
    //   bias_s1   : 1088 fp32 [bdkv|bdq|bkr];  bias_2: 4096 fp32 [buk|buv|buq|bqr]
    char* ws = (char*)d_ws;
    u16* out1   = (u16*)ws;                              // 17,825,792 B
    u16* hbf    = (u16*)(ws + 17825792);                 // 33,554,432 B (= out2a)
    u16* out2a  = hbf;
    u16* out2b  = (u16*)(ws + 51380224);                 // 33,554,432 B
    u16* w1     = (u16*)(ws + 84934656);                 //  4,718,592 B
    u16* w2a    = (u16*)(ws + 89653248);                 //  2,097,152 B
    u16* w2b    = (u16*)(ws + 91750400);                 //  2,097,152 B
    u16* wfc    = (u16*)(ws + 93847552);                 //  4,194,304 B
    float* bias_s1 = (float*)(ws + 98041856);            //      4,352 B
    float* bias_2  = (float*)(ws + 98046208);            //     16,384 B

    // --- conversion pass: h + all weights -> bf16 (8-elem chunks) ---
    Cvt9 cd;
    const float* srcs[9] = { h, Wdkv, Wdq, Wkr, Wuk, Wuv, Wuq, Wqr, Wfc };
    u16* dsts[9] = { hbf, w1, w1 + 512 * 2048, w1 + 1024 * 2048,
                     w2a, w2a + 1024 * 512, w2b, w2b + 1024 * 512, wfc };
    int cnts[9] = { 2097152, 131072, 131072, 16384, 65536, 65536, 65536, 65536, 262144 };
    int acc2 = 0;
    for (int i = 0; i < 9; ++i) { cd.src[i] = srcs[i]; cd.dst[i] = dsts[i]; acc2 += cnts[i]; cd.end[i] = acc2; }
    cvt_all<<<(acc2 + 255) / 256, 256, 0, stream>>>(cd, acc2);
    // zero-pad w1 rows 1088..1151
    hipMemsetAsync(w1 + 1088 * 2048, 0, 64 * 2048 * sizeof(u16), stream);

    // --- bias concat (fp32) ---
    Cpy7 bc;
    const float* bs[7] = { bdkv, bdq, bkr, buk, buv, buq, bqr };
    float* bd[7] = { bias_s1, bias_s1 + 512, bias_s1 + 1024,
                     bias_2, bias_2 + 1024, bias_2 + 2048, bias_2 + 3072 };
    int bn[7] = { 512, 512, 64, 1024, 1024, 1024, 1024 };
    int bacc = 0;
    for (int i = 0; i < 7; ++i) { bc.src[i] = bs[i]; bc.dst[i] = bd[i]; bacc += bn[i]; bc.end[i] = bacc; }
    copy_f32<<<(bacc + 255) / 256, 256, 0, stream>>>(bc, bacc);

    // --- stage 1: [c_kv|c_q|k_r] = hbf @ w1^T, N=1088, K=2048; fused k_r rope ---
    gemm_v7<false><<<dim3(64, 9), 256, 0, stream>>>(
        hbf, w1, out1, bias_s1,
        hbf, w1, out1, bias_s1, 9, 2048, 2048, 1088, 1088, 2048, 1, 1);

    // --- stage 2 (fused 2a+2b): K=512, N=2048 each half; fused q_r rope on 2b ---
    gemm_v7<false><<<dim3(64, 32), 256, 0, stream>>>(
        out1,       w2a, out2a, bias_2,
        out1 + 512, w2b, out2b, bias_2 + 2048, 16, 1088, 512, 2048, 2048, 512, 0, 1);

    // --- attention: 1024 WG x 512 thr, temporal XCD swizzle in-kernel ---
    attn_kernel<<<1024, 512, 0, stream>>>(out2b, out2a, out1, out1, 1088);

    // --- final projection: d_out = attn @ wfc^T, fp32 out ---
    gemm_v7<true><<<dim3(64, 16), 256, 0, stream>>>(
        out1, wfc, d_out, bfc,
        out1, wfc, d_out, bfc, 16, 1088, 1024, 2048, 2048, 1024, 0, 0);
}